// Round 1
// baseline (593.070 us; speedup 1.0000x reference)
//
#include <hip/hip_runtime.h>
#include <hip/hip_bf16.h>

typedef unsigned int uint;
typedef unsigned short ushort;
typedef __attribute__((ext_vector_type(8))) short short8;
typedef __attribute__((ext_vector_type(4))) float f32x4;

__device__ __forceinline__ float bf2f(ushort u) {
    union { uint i; float f; } v; v.i = ((uint)u) << 16; return v.f;
}
__device__ __forceinline__ ushort f2bf(float f) {
    union { float f; uint i; } v; v.f = f;
    uint x = v.i;
    uint r = (x + 0x7FFFu + ((x >> 16) & 1u)) >> 16;
    return (ushort)r;
}

// ---------------- graph prep ----------------

__global__ void k_degree(const int* __restrict__ dst, int* __restrict__ deg, int e) {
    int i = blockIdx.x * 256 + threadIdx.x;
    if (i < e) atomicAdd(&deg[dst[i]], 1);
}

__global__ void k_dinv(const int* __restrict__ deg, float* __restrict__ dinv, int n) {
    int i = blockIdx.x * 256 + threadIdx.x;
    if (i < n) dinv[i] = rsqrtf((float)deg[i] + 1.0f);  // +1 self-loop
}

// 3-kernel exclusive scan of edge-degree -> offsets. chunk = 1024/block.
__global__ void k_scan_a(const int* __restrict__ deg, int* __restrict__ bsum, int n) {
    __shared__ int sd[256];
    int t = threadIdx.x;
    int base = blockIdx.x * 1024 + t * 4;
    int s = 0;
#pragma unroll
    for (int j = 0; j < 4; ++j) { int idx = base + j; if (idx < n) s += deg[idx]; }
    sd[t] = s; __syncthreads();
    for (int off = 1; off < 256; off <<= 1) {
        int v = (t >= off) ? sd[t - off] : 0;
        __syncthreads();
        sd[t] += v;
        __syncthreads();
    }
    if (t == 255) bsum[blockIdx.x] = sd[255];
}

__global__ void k_scan_b(const int* __restrict__ bsum, int* __restrict__ boff, int nb) {
    __shared__ int sd[256];
    int t = threadIdx.x;
    int v0 = (t < nb) ? bsum[t] : 0;
    sd[t] = v0; __syncthreads();
    for (int off = 1; off < 256; off <<= 1) {
        int v = (t >= off) ? sd[t - off] : 0;
        __syncthreads();
        sd[t] += v;
        __syncthreads();
    }
    if (t < nb) boff[t] = sd[t] - v0;  // exclusive
}

__global__ void k_scan_c(const int* __restrict__ deg, const int* __restrict__ boff,
                         int* __restrict__ offs, int n) {
    __shared__ int sd[256];
    int t = threadIdx.x;
    int base = blockIdx.x * 1024 + t * 4;
    int vals[4]; int s = 0;
#pragma unroll
    for (int j = 0; j < 4; ++j) {
        int idx = base + j;
        vals[j] = (idx < n) ? deg[idx] : 0;
        s += vals[j];
    }
    sd[t] = s; __syncthreads();
    for (int off = 1; off < 256; off <<= 1) {
        int v = (t >= off) ? sd[t - off] : 0;
        __syncthreads();
        sd[t] += v;
        __syncthreads();
    }
    int run = boff[blockIdx.x] + (sd[t] - s);
#pragma unroll
    for (int j = 0; j < 4; ++j) {
        int idx = base + j;
        if (idx < n) { offs[idx] = run; run += vals[j]; }
    }
}

__global__ void k_fill(const int* __restrict__ src, const int* __restrict__ dst,
                       const int* __restrict__ offs, int* __restrict__ cursor,
                       int* __restrict__ csr, int e) {
    int i = blockIdx.x * 256 + threadIdx.x;
    if (i < e) {
        int d = dst[i];
        int p = offs[d] + atomicAdd(&cursor[d], 1);
        csr[p] = src[i];
    }
}

// ---------------- GEMM1: h1 = x@W1 (bf16), xfc = relu(x@We+be) (bf16) ----------------
// block: 512 thr = 8 waves, 128 rows/block. B staged in LDS split-K (2 stages of 64).

__global__ __launch_bounds__(512) void k_gemm1(
    const float* __restrict__ x, const float* __restrict__ W1, const float* __restrict__ We,
    const float* __restrict__ be, ushort* __restrict__ h1, ushort* __restrict__ xfc, int n)
{
    __shared__ __align__(16) ushort Bt[256][72];  // [col][k_local], pad 72 for banks
    int tid = threadIdx.x;
    int w = tid >> 6, lane = tid & 63;
    int ln15 = lane & 15, g = lane >> 4;
    int rowBase = blockIdx.x * 128 + w * 16;
    int r = rowBase + ln15;
    bool valid = r < n;

    // A fragments: row r, k = ks*32 + g*8 .. +7 (f32 -> bf16)
    short8 a[4];
#pragma unroll
    for (int ks = 0; ks < 4; ++ks) {
        float4 f0 = make_float4(0.f, 0.f, 0.f, 0.f), f1 = f0;
        if (valid) {
            const float* p = x + (size_t)r * 128 + ks * 32 + g * 8;
            f0 = *reinterpret_cast<const float4*>(p);
            f1 = *reinterpret_cast<const float4*>(p + 4);
        }
        short8 v;
        v[0] = (short)f2bf(f0.x); v[1] = (short)f2bf(f0.y);
        v[2] = (short)f2bf(f0.z); v[3] = (short)f2bf(f0.w);
        v[4] = (short)f2bf(f1.x); v[5] = (short)f2bf(f1.y);
        v[6] = (short)f2bf(f1.z); v[7] = (short)f2bf(f1.w);
        a[ks] = v;
    }

    f32x4 acc[16];
#pragma unroll
    for (int i = 0; i < 16; ++i) acc[i] = (f32x4){0.f, 0.f, 0.f, 0.f};

    for (int s = 0; s < 2; ++s) {
        // stage W1/We rows k = s*64 .. s*64+63, transposed -> Bt[col][k_local]
        for (int i = tid; i < 8192; i += 512) {
            int kl = i >> 7, j = i & 127;
            int kg = s * 64 + kl;
            Bt[j][kl]       = f2bf(W1[kg * 128 + j]);
            Bt[128 + j][kl] = f2bf(We[kg * 128 + j]);
        }
        __syncthreads();
#pragma unroll
        for (int t2 = 0; t2 < 2; ++t2) {
            short8 af = a[s * 2 + t2];
#pragma unroll
            for (int jf = 0; jf < 16; ++jf) {
                short8 bf = *reinterpret_cast<const short8*>(&Bt[jf * 16 + ln15][t2 * 32 + g * 8]);
                acc[jf] = __builtin_amdgcn_mfma_f32_16x16x32_bf16(af, bf, acc[jf], 0, 0, 0);
            }
        }
        __syncthreads();
    }

    // D layout: col = lane&15, row = (lane>>4)*4 + q
#pragma unroll
    for (int jf = 0; jf < 16; ++jf) {
        int col = jf * 16 + ln15;
#pragma unroll
        for (int q = 0; q < 4; ++q) {
            int rr = rowBase + g * 4 + q;
            if (rr < n) {
                float v = acc[jf][q];
                if (col < 128) {
                    h1[(size_t)rr * 128 + col] = f2bf(v);
                } else {
                    float vv = fmaxf(v + be[col - 128], 0.f);
                    xfc[(size_t)rr * 128 + (col - 128)] = f2bf(vv);
                }
            }
        }
    }
}

// ---------------- GEMM2: h2 = h@W2 (bf16 in, bf16 out) ----------------

__global__ __launch_bounds__(512) void k_gemm2(
    const ushort* __restrict__ h, const float* __restrict__ W2, ushort* __restrict__ h2, int n)
{
    __shared__ __align__(16) ushort Bt[128][72];
    int tid = threadIdx.x;
    int w = tid >> 6, lane = tid & 63;
    int ln15 = lane & 15, g = lane >> 4;
    int rowBase = blockIdx.x * 128 + w * 16;
    int r = rowBase + ln15;
    bool valid = r < n;

    short8 a[4];
#pragma unroll
    for (int ks = 0; ks < 4; ++ks) {
        short8 v = (short8){0,0,0,0,0,0,0,0};
        if (valid) v = *reinterpret_cast<const short8*>(h + (size_t)r * 128 + ks * 32 + g * 8);
        a[ks] = v;
    }

    f32x4 acc[8];
#pragma unroll
    for (int i = 0; i < 8; ++i) acc[i] = (f32x4){0.f, 0.f, 0.f, 0.f};

    for (int s = 0; s < 2; ++s) {
        for (int i = tid; i < 8192; i += 512) {
            int kl = i >> 7, j = i & 127;
            Bt[j][kl] = f2bf(W2[(s * 64 + kl) * 128 + j]);
        }
        __syncthreads();
#pragma unroll
        for (int t2 = 0; t2 < 2; ++t2) {
            short8 af = a[s * 2 + t2];
#pragma unroll
            for (int jf = 0; jf < 8; ++jf) {
                short8 bf = *reinterpret_cast<const short8*>(&Bt[jf * 16 + ln15][t2 * 32 + g * 8]);
                acc[jf] = __builtin_amdgcn_mfma_f32_16x16x32_bf16(af, bf, acc[jf], 0, 0, 0);
            }
        }
        __syncthreads();
    }

#pragma unroll
    for (int jf = 0; jf < 8; ++jf) {
        int col = jf * 16 + ln15;
#pragma unroll
        for (int q = 0; q < 4; ++q) {
            int rr = rowBase + g * 4 + q;
            if (rr < n) h2[(size_t)rr * 128 + col] = f2bf(acc[jf][q]);
        }
    }
}

// ---------------- aggregation 1: h = relu(D^-1/2 A D^-1/2 h1 + b1) + xfc ----------------
// one wave per node, lane owns channels 2*lane, 2*lane+1

__global__ __launch_bounds__(256) void k_agg1(
    const int* __restrict__ csr, const int* __restrict__ offs, const int* __restrict__ degE,
    const float* __restrict__ dinv, const ushort* __restrict__ h1, const ushort* __restrict__ xfc,
    const float* __restrict__ b1, ushort* __restrict__ h, int n)
{
    int wid = threadIdx.x >> 6, lane = threadIdx.x & 63;
    int node = blockIdx.x * 4 + wid;
    if (node >= n) return;
    int off = offs[node], cnt = degE[node];
    int c0 = lane * 2;
    float acc0 = 0.f, acc1 = 0.f;
    for (int base = 0; base < cnt; base += 64) {
        int k = base + lane;
        int s = 0; float wsc = 0.f;
        if (k < cnt) { s = csr[off + k]; wsc = dinv[s]; }
        int m = min(64, cnt - base);
        for (int j = 0; j < m; ++j) {
            int sj = __shfl(s, j);
            float wj = __shfl(wsc, j);
            uint u = *reinterpret_cast<const uint*>(h1 + (size_t)sj * 128 + c0);
            acc0 += wj * bf2f((ushort)(u & 0xffff));
            acc1 += wj * bf2f((ushort)(u >> 16));
        }
    }
    float di = dinv[node];
    uint us = *reinterpret_cast<const uint*>(h1 + (size_t)node * 128 + c0);
    float v0 = fmaxf(di * acc0 + di * di * bf2f((ushort)(us & 0xffff)) + b1[c0], 0.f);
    float v1 = fmaxf(di * acc1 + di * di * bf2f((ushort)(us >> 16)) + b1[c0 + 1], 0.f);
    uint ux = *reinterpret_cast<const uint*>(xfc + (size_t)node * 128 + c0);
    v0 += bf2f((ushort)(ux & 0xffff));
    v1 += bf2f((ushort)(ux >> 16));
    uint outw = (uint)f2bf(v0) | ((uint)f2bf(v1) << 16);
    *reinterpret_cast<uint*>(h + (size_t)node * 128 + c0) = outw;
}

// ---------------- aggregation 2 + residual + pool partial ----------------

__global__ __launch_bounds__(256) void k_agg2(
    const int* __restrict__ csr, const int* __restrict__ offs, const int* __restrict__ degE,
    const float* __restrict__ dinv, const ushort* __restrict__ h2, const ushort* __restrict__ hres,
    const float* __restrict__ b2, float* __restrict__ pooled, int n)
{
    __shared__ float lpool[128];
    int t = threadIdx.x;
    if (t < 128) lpool[t] = 0.f;
    __syncthreads();
    int wid = t >> 6, lane = t & 63, c0 = lane * 2;
    float p0 = 0.f, p1 = 0.f;
    for (int q = 0; q < 4; ++q) {
        int node = blockIdx.x * 16 + wid * 4 + q;
        if (node >= n) continue;
        int off = offs[node], cnt = degE[node];
        float acc0 = 0.f, acc1 = 0.f;
        for (int base = 0; base < cnt; base += 64) {
            int k = base + lane;
            int s = 0; float wsc = 0.f;
            if (k < cnt) { s = csr[off + k]; wsc = dinv[s]; }
            int m = min(64, cnt - base);
            for (int j = 0; j < m; ++j) {
                int sj = __shfl(s, j);
                float wj = __shfl(wsc, j);
                uint u = *reinterpret_cast<const uint*>(h2 + (size_t)sj * 128 + c0);
                acc0 += wj * bf2f((ushort)(u & 0xffff));
                acc1 += wj * bf2f((ushort)(u >> 16));
            }
        }
        float di = dinv[node];
        uint us = *reinterpret_cast<const uint*>(h2 + (size_t)node * 128 + c0);
        float v0 = fmaxf(di * acc0 + di * di * bf2f((ushort)(us & 0xffff)) + b2[c0], 0.f);
        float v1 = fmaxf(di * acc1 + di * di * bf2f((ushort)(us >> 16)) + b2[c0 + 1], 0.f);
        uint ur = *reinterpret_cast<const uint*>(hres + (size_t)node * 128 + c0);
        p0 += v0 + bf2f((ushort)(ur & 0xffff));
        p1 += v1 + bf2f((ushort)(ur >> 16));
    }
    atomicAdd(&lpool[c0], p0);
    atomicAdd(&lpool[c0 + 1], p1);
    __syncthreads();
    if (t < 128) atomicAdd(&pooled[t], lpool[t]);
}

// ---------------- final: sigmoid(mean @ Wfc + bfc) ----------------

__global__ void k_final(const float* __restrict__ pooled, const float* __restrict__ Wfc,
                        const float* __restrict__ bfc, float* __restrict__ out, float invN) {
    int lane = threadIdx.x;
    float s = pooled[2 * lane] * invN * Wfc[2 * lane] +
              pooled[2 * lane + 1] * invN * Wfc[2 * lane + 1];
#pragma unroll
    for (int off = 32; off > 0; off >>= 1) s += __shfl_down(s, off);
    if (lane == 0) out[0] = 1.f / (1.f + expf(-(s + bfc[0])));
}

// ---------------- launch ----------------

extern "C" void kernel_launch(void* const* d_in, const int* in_sizes, int n_in,
                              void* d_out, int out_size, void* d_ws, size_t ws_size,
                              hipStream_t stream) {
    const float* x   = (const float*)d_in[0];
    const int*   ei  = (const int*)d_in[1];
    const float* W1  = (const float*)d_in[2];
    const float* b1  = (const float*)d_in[3];
    const float* W2  = (const float*)d_in[4];
    const float* b2  = (const float*)d_in[5];
    const float* We  = (const float*)d_in[6];
    const float* be  = (const float*)d_in[7];
    const float* Wfc = (const float*)d_in[8];
    const float* bfc = (const float*)d_in[9];
    float* out = (float*)d_out;

    const int N = in_sizes[0] / 128;
    const int E = in_sizes[1] / 2;
    const int* src = ei;
    const int* dst = ei + E;

    char* w = (char*)d_ws;
    size_t off = 0;
    auto take = [&](size_t bytes) -> void* {
        void* p = w + off;
        off = (off + bytes + 255) & ~(size_t)255;
        return p;
    };
    int*    deg    = (int*)take((size_t)N * 4);
    int*    offs   = (int*)take((size_t)N * 4);
    int*    cursor = (int*)take((size_t)N * 4);
    float*  dinv   = (float*)take((size_t)N * 4);
    int*    bsum   = (int*)take(1024);
    int*    boff   = (int*)take(1024);
    int*    csr    = (int*)take((size_t)E * 4);
    ushort* h1     = (ushort*)take((size_t)N * 128 * 2);
    ushort* xfc    = (ushort*)take((size_t)N * 128 * 2);
    ushort* h      = (ushort*)take((size_t)N * 128 * 2);
    ushort* h2     = (ushort*)take((size_t)N * 128 * 2);
    float*  pooled = (float*)take(512);

    const int nbE = (E + 255) / 256;
    const int nbScan = (N + 1023) / 1024;

    hipMemsetAsync(deg, 0, (size_t)N * 4, stream);
    hipMemsetAsync(cursor, 0, (size_t)N * 4, stream);
    hipMemsetAsync(pooled, 0, 512, stream);

    k_degree<<<nbE, 256, 0, stream>>>(dst, deg, E);
    k_dinv<<<(N + 255) / 256, 256, 0, stream>>>(deg, dinv, N);
    k_scan_a<<<nbScan, 256, 0, stream>>>(deg, bsum, N);
    k_scan_b<<<1, 256, 0, stream>>>(bsum, boff, nbScan);
    k_scan_c<<<nbScan, 256, 0, stream>>>(deg, boff, offs, N);
    k_fill<<<nbE, 256, 0, stream>>>(src, dst, offs, cursor, csr, E);

    k_gemm1<<<(N + 127) / 128, 512, 0, stream>>>(x, W1, We, be, h1, xfc, N);
    k_agg1<<<(N + 3) / 4, 256, 0, stream>>>(csr, offs, deg, dinv, h1, xfc, b1, h, N);
    k_gemm2<<<(N + 127) / 128, 512, 0, stream>>>(h, W2, h2, N);
    k_agg2<<<(N + 15) / 16, 256, 0, stream>>>(csr, offs, deg, dinv, h2, h, b2, pooled, N);
    k_final<<<1, 64, 0, stream>>>(pooled, Wfc, bfc, out, 1.0f / (float)N);
}

// Round 2
// 483.255 us; speedup vs baseline: 1.2272x; 1.2272x over previous
//
#include <hip/hip_runtime.h>
#include <hip/hip_bf16.h>

typedef unsigned int uint;
typedef unsigned short ushort;
typedef __attribute__((ext_vector_type(8))) short short8;
typedef __attribute__((ext_vector_type(4))) float f32x4;

__device__ __forceinline__ float bf2f(ushort u) {
    union { uint i; float f; } v; v.i = ((uint)u) << 16; return v.f;
}
__device__ __forceinline__ ushort f2bf(float f) {
    union { float f; uint i; } v; v.f = f;
    uint x = v.i;
    uint r = (x + 0x7FFFu + ((x >> 16) & 1u)) >> 16;
    return (ushort)r;
}

// ---------------- graph prep ----------------

__global__ void k_degree(const int* __restrict__ dst, int* __restrict__ deg, int e) {
    int i = blockIdx.x * 256 + threadIdx.x;
    if (i < e) atomicAdd(&deg[dst[i]], 1);
}

__global__ void k_dinv(const int* __restrict__ deg, float* __restrict__ dinv, int n) {
    int i = blockIdx.x * 256 + threadIdx.x;
    if (i < n) dinv[i] = rsqrtf((float)deg[i] + 1.0f);  // +1 self-loop
}

// 3-kernel exclusive scan of edge-degree -> offsets. chunk = 1024/block.
__global__ void k_scan_a(const int* __restrict__ deg, int* __restrict__ bsum, int n) {
    __shared__ int sd[256];
    int t = threadIdx.x;
    int base = blockIdx.x * 1024 + t * 4;
    int s = 0;
#pragma unroll
    for (int j = 0; j < 4; ++j) { int idx = base + j; if (idx < n) s += deg[idx]; }
    sd[t] = s; __syncthreads();
    for (int off = 1; off < 256; off <<= 1) {
        int v = (t >= off) ? sd[t - off] : 0;
        __syncthreads();
        sd[t] += v;
        __syncthreads();
    }
    if (t == 255) bsum[blockIdx.x] = sd[255];
}

__global__ void k_scan_b(const int* __restrict__ bsum, int* __restrict__ boff, int nb) {
    __shared__ int sd[256];
    int t = threadIdx.x;
    int v0 = (t < nb) ? bsum[t] : 0;
    sd[t] = v0; __syncthreads();
    for (int off = 1; off < 256; off <<= 1) {
        int v = (t >= off) ? sd[t - off] : 0;
        __syncthreads();
        sd[t] += v;
        __syncthreads();
    }
    if (t < nb) boff[t] = sd[t] - v0;  // exclusive
}

__global__ void k_scan_c(const int* __restrict__ deg, const int* __restrict__ boff,
                         int* __restrict__ offs, int n) {
    __shared__ int sd[256];
    int t = threadIdx.x;
    int base = blockIdx.x * 1024 + t * 4;
    int vals[4]; int s = 0;
#pragma unroll
    for (int j = 0; j < 4; ++j) {
        int idx = base + j;
        vals[j] = (idx < n) ? deg[idx] : 0;
        s += vals[j];
    }
    sd[t] = s; __syncthreads();
    for (int off = 1; off < 256; off <<= 1) {
        int v = (t >= off) ? sd[t - off] : 0;
        __syncthreads();
        sd[t] += v;
        __syncthreads();
    }
    int run = boff[blockIdx.x] + (sd[t] - s);
#pragma unroll
    for (int j = 0; j < 4; ++j) {
        int idx = base + j;
        if (idx < n) { offs[idx] = run; run += vals[j]; }
    }
}

__global__ void k_fill(const int* __restrict__ src, const int* __restrict__ dst,
                       const int* __restrict__ offs, int* __restrict__ cursor,
                       int* __restrict__ csr, int e) {
    int i = blockIdx.x * 256 + threadIdx.x;
    if (i < e) {
        int d = dst[i];
        int p = offs[d] + atomicAdd(&cursor[d], 1);
        csr[p] = src[i];
    }
}

// ---------------- GEMM1: h1 = x@W1 (bf16), xfc = relu(x@We+be) (bf16) ----------------

__global__ __launch_bounds__(512) void k_gemm1(
    const float* __restrict__ x, const float* __restrict__ W1, const float* __restrict__ We,
    const float* __restrict__ be, ushort* __restrict__ h1, ushort* __restrict__ xfc, int n)
{
    __shared__ __align__(16) ushort Bt[256][72];  // [col][k_local], pad 72 for banks
    int tid = threadIdx.x;
    int w = tid >> 6, lane = tid & 63;
    int ln15 = lane & 15, g = lane >> 4;
    int rowBase = blockIdx.x * 128 + w * 16;
    int r = rowBase + ln15;
    bool valid = r < n;

    short8 a[4];
#pragma unroll
    for (int ks = 0; ks < 4; ++ks) {
        float4 f0 = make_float4(0.f, 0.f, 0.f, 0.f), f1 = f0;
        if (valid) {
            const float* p = x + (size_t)r * 128 + ks * 32 + g * 8;
            f0 = *reinterpret_cast<const float4*>(p);
            f1 = *reinterpret_cast<const float4*>(p + 4);
        }
        short8 v;
        v[0] = (short)f2bf(f0.x); v[1] = (short)f2bf(f0.y);
        v[2] = (short)f2bf(f0.z); v[3] = (short)f2bf(f0.w);
        v[4] = (short)f2bf(f1.x); v[5] = (short)f2bf(f1.y);
        v[6] = (short)f2bf(f1.z); v[7] = (short)f2bf(f1.w);
        a[ks] = v;
    }

    f32x4 acc[16];
#pragma unroll
    for (int i = 0; i < 16; ++i) acc[i] = (f32x4){0.f, 0.f, 0.f, 0.f};

    for (int s = 0; s < 2; ++s) {
        for (int i = tid; i < 8192; i += 512) {
            int kl = i >> 7, j = i & 127;
            int kg = s * 64 + kl;
            Bt[j][kl]       = f2bf(W1[kg * 128 + j]);
            Bt[128 + j][kl] = f2bf(We[kg * 128 + j]);
        }
        __syncthreads();
#pragma unroll
        for (int t2 = 0; t2 < 2; ++t2) {
            short8 af = a[s * 2 + t2];
#pragma unroll
            for (int jf = 0; jf < 16; ++jf) {
                short8 bf = *reinterpret_cast<const short8*>(&Bt[jf * 16 + ln15][t2 * 32 + g * 8]);
                acc[jf] = __builtin_amdgcn_mfma_f32_16x16x32_bf16(af, bf, acc[jf], 0, 0, 0);
            }
        }
        __syncthreads();
    }

    // D layout: col = lane&15, row = (lane>>4)*4 + q
#pragma unroll
    for (int jf = 0; jf < 16; ++jf) {
        int col = jf * 16 + ln15;
#pragma unroll
        for (int q = 0; q < 4; ++q) {
            int rr = rowBase + g * 4 + q;
            if (rr < n) {
                float v = acc[jf][q];
                if (col < 128) {
                    h1[(size_t)rr * 128 + col] = f2bf(v);
                } else {
                    float vv = fmaxf(v + be[col - 128], 0.f);
                    xfc[(size_t)rr * 128 + (col - 128)] = f2bf(vv);
                }
            }
        }
    }
}

// ---------------- GEMM2: h2 = h@W2 (bf16 in, bf16 out) ----------------

__global__ __launch_bounds__(512) void k_gemm2(
    const ushort* __restrict__ h, const float* __restrict__ W2, ushort* __restrict__ h2, int n)
{
    __shared__ __align__(16) ushort Bt[128][72];
    int tid = threadIdx.x;
    int w = tid >> 6, lane = tid & 63;
    int ln15 = lane & 15, g = lane >> 4;
    int rowBase = blockIdx.x * 128 + w * 16;
    int r = rowBase + ln15;
    bool valid = r < n;

    short8 a[4];
#pragma unroll
    for (int ks = 0; ks < 4; ++ks) {
        short8 v = (short8){0,0,0,0,0,0,0,0};
        if (valid) v = *reinterpret_cast<const short8*>(h + (size_t)r * 128 + ks * 32 + g * 8);
        a[ks] = v;
    }

    f32x4 acc[8];
#pragma unroll
    for (int i = 0; i < 8; ++i) acc[i] = (f32x4){0.f, 0.f, 0.f, 0.f};

    for (int s = 0; s < 2; ++s) {
        for (int i = tid; i < 8192; i += 512) {
            int kl = i >> 7, j = i & 127;
            Bt[j][kl] = f2bf(W2[(s * 64 + kl) * 128 + j]);
        }
        __syncthreads();
#pragma unroll
        for (int t2 = 0; t2 < 2; ++t2) {
            short8 af = a[s * 2 + t2];
#pragma unroll
            for (int jf = 0; jf < 8; ++jf) {
                short8 bf = *reinterpret_cast<const short8*>(&Bt[jf * 16 + ln15][t2 * 32 + g * 8]);
                acc[jf] = __builtin_amdgcn_mfma_f32_16x16x32_bf16(af, bf, acc[jf], 0, 0, 0);
            }
        }
        __syncthreads();
    }

#pragma unroll
    for (int jf = 0; jf < 8; ++jf) {
        int col = jf * 16 + ln15;
#pragma unroll
        for (int q = 0; q < 4; ++q) {
            int rr = rowBase + g * 4 + q;
            if (rr < n) h2[(size_t)rr * 128 + col] = f2bf(acc[jf][q]);
        }
    }
}

// ---------------- aggregation 1: h = relu(D^-1/2 A D^-1/2 h1 + b1) + xfc ----------------
// one wave per node; lane owns channels 2*lane, 2*lane+1.
// Edge loop unrolled x8 to keep 8 independent row-gathers in flight (MLP).
// Lanes with k >= cnt hold wsc=0/s=0 so the unrolled batch needs no tail
// (j <= 56 so shfl index j+q <= 63 always).

__global__ __launch_bounds__(256) void k_agg1(
    const int* __restrict__ csr, const int* __restrict__ offs, const int* __restrict__ degE,
    const float* __restrict__ dinv, const ushort* __restrict__ h1, const ushort* __restrict__ xfc,
    const float* __restrict__ b1, ushort* __restrict__ h, int n)
{
    int wid = threadIdx.x >> 6, lane = threadIdx.x & 63;
    int node = blockIdx.x * 4 + wid;
    if (node >= n) return;
    int off = offs[node], cnt = degE[node];
    int c0 = lane * 2;
    float acc0 = 0.f, acc1 = 0.f;
    for (int base = 0; base < cnt; base += 64) {
        int k = base + lane;
        int s = 0; float wsc = 0.f;
        if (k < cnt) { s = csr[off + k]; wsc = dinv[s]; }
        int m = min(64, cnt - base);
        for (int j = 0; j < m; j += 8) {
            int sj[8]; float wj[8]; uint u[8];
#pragma unroll
            for (int q = 0; q < 8; ++q) {
                sj[q] = __shfl(s, j + q);
                wj[q] = __shfl(wsc, j + q);
            }
#pragma unroll
            for (int q = 0; q < 8; ++q)
                u[q] = *reinterpret_cast<const uint*>(h1 + (size_t)sj[q] * 128 + c0);
#pragma unroll
            for (int q = 0; q < 8; ++q) {
                acc0 += wj[q] * bf2f((ushort)(u[q] & 0xffff));
                acc1 += wj[q] * bf2f((ushort)(u[q] >> 16));
            }
        }
    }
    float di = dinv[node];
    uint us = *reinterpret_cast<const uint*>(h1 + (size_t)node * 128 + c0);
    float v0 = fmaxf(di * acc0 + di * di * bf2f((ushort)(us & 0xffff)) + b1[c0], 0.f);
    float v1 = fmaxf(di * acc1 + di * di * bf2f((ushort)(us >> 16)) + b1[c0 + 1], 0.f);
    uint ux = *reinterpret_cast<const uint*>(xfc + (size_t)node * 128 + c0);
    v0 += bf2f((ushort)(ux & 0xffff));
    v1 += bf2f((ushort)(ux >> 16));
    uint outw = (uint)f2bf(v0) | ((uint)f2bf(v1) << 16);
    *reinterpret_cast<uint*>(h + (size_t)node * 128 + c0) = outw;
}

// ---------------- aggregation 2 + residual + pool partial ----------------

__global__ __launch_bounds__(256) void k_agg2(
    const int* __restrict__ csr, const int* __restrict__ offs, const int* __restrict__ degE,
    const float* __restrict__ dinv, const ushort* __restrict__ h2, const ushort* __restrict__ hres,
    const float* __restrict__ b2, float* __restrict__ pooled, int n)
{
    __shared__ float lpool[128];
    int t = threadIdx.x;
    if (t < 128) lpool[t] = 0.f;
    __syncthreads();
    int wid = t >> 6, lane = t & 63, c0 = lane * 2;
    float p0 = 0.f, p1 = 0.f;
    for (int q4 = 0; q4 < 4; ++q4) {
        int node = blockIdx.x * 16 + wid * 4 + q4;
        if (node >= n) continue;
        int off = offs[node], cnt = degE[node];
        float acc0 = 0.f, acc1 = 0.f;
        for (int base = 0; base < cnt; base += 64) {
            int k = base + lane;
            int s = 0; float wsc = 0.f;
            if (k < cnt) { s = csr[off + k]; wsc = dinv[s]; }
            int m = min(64, cnt - base);
            for (int j = 0; j < m; j += 8) {
                int sj[8]; float wj[8]; uint u[8];
#pragma unroll
                for (int q = 0; q < 8; ++q) {
                    sj[q] = __shfl(s, j + q);
                    wj[q] = __shfl(wsc, j + q);
                }
#pragma unroll
                for (int q = 0; q < 8; ++q)
                    u[q] = *reinterpret_cast<const uint*>(h2 + (size_t)sj[q] * 128 + c0);
#pragma unroll
                for (int q = 0; q < 8; ++q) {
                    acc0 += wj[q] * bf2f((ushort)(u[q] & 0xffff));
                    acc1 += wj[q] * bf2f((ushort)(u[q] >> 16));
                }
            }
        }
        float di = dinv[node];
        uint us = *reinterpret_cast<const uint*>(h2 + (size_t)node * 128 + c0);
        float v0 = fmaxf(di * acc0 + di * di * bf2f((ushort)(us & 0xffff)) + b2[c0], 0.f);
        float v1 = fmaxf(di * acc1 + di * di * bf2f((ushort)(us >> 16)) + b2[c0 + 1], 0.f);
        uint ur = *reinterpret_cast<const uint*>(hres + (size_t)node * 128 + c0);
        p0 += v0 + bf2f((ushort)(ur & 0xffff));
        p1 += v1 + bf2f((ushort)(ur >> 16));
    }
    atomicAdd(&lpool[c0], p0);
    atomicAdd(&lpool[c0 + 1], p1);
    __syncthreads();
    if (t < 128) atomicAdd(&pooled[t], lpool[t]);
}

// ---------------- final: sigmoid(mean @ Wfc + bfc) ----------------

__global__ void k_final(const float* __restrict__ pooled, const float* __restrict__ Wfc,
                        const float* __restrict__ bfc, float* __restrict__ out, float invN) {
    int lane = threadIdx.x;
    float s = pooled[2 * lane] * invN * Wfc[2 * lane] +
              pooled[2 * lane + 1] * invN * Wfc[2 * lane + 1];
#pragma unroll
    for (int off = 32; off > 0; off >>= 1) s += __shfl_down(s, off);
    if (lane == 0) out[0] = 1.f / (1.f + expf(-(s + bfc[0])));
}

// ---------------- launch ----------------

extern "C" void kernel_launch(void* const* d_in, const int* in_sizes, int n_in,
                              void* d_out, int out_size, void* d_ws, size_t ws_size,
                              hipStream_t stream) {
    const float* x   = (const float*)d_in[0];
    const int*   ei  = (const int*)d_in[1];
    const float* W1  = (const float*)d_in[2];
    const float* b1  = (const float*)d_in[3];
    const float* W2  = (const float*)d_in[4];
    const float* b2  = (const float*)d_in[5];
    const float* We  = (const float*)d_in[6];
    const float* be  = (const float*)d_in[7];
    const float* Wfc = (const float*)d_in[8];
    const float* bfc = (const float*)d_in[9];
    float* out = (float*)d_out;

    const int N = in_sizes[0] / 128;
    const int E = in_sizes[1] / 2;
    const int* src = ei;
    const int* dst = ei + E;

    char* w = (char*)d_ws;
    size_t off = 0;
    auto take = [&](size_t bytes) -> void* {
        void* p = w + off;
        off = (off + bytes + 255) & ~(size_t)255;
        return p;
    };
    int*    deg    = (int*)take((size_t)N * 4);
    int*    offs   = (int*)take((size_t)N * 4);
    int*    cursor = (int*)take((size_t)N * 4);
    float*  dinv   = (float*)take((size_t)N * 4);
    int*    bsum   = (int*)take(1024);
    int*    boff   = (int*)take(1024);
    int*    csr    = (int*)take((size_t)E * 4);
    ushort* h1     = (ushort*)take((size_t)N * 128 * 2);
    ushort* xfc    = (ushort*)take((size_t)N * 128 * 2);
    ushort* h      = (ushort*)take((size_t)N * 128 * 2);
    ushort* h2     = (ushort*)take((size_t)N * 128 * 2);
    float*  pooled = (float*)take(512);

    const int nbE = (E + 255) / 256;
    const int nbScan = (N + 1023) / 1024;

    hipMemsetAsync(deg, 0, (size_t)N * 4, stream);
    hipMemsetAsync(cursor, 0, (size_t)N * 4, stream);
    hipMemsetAsync(pooled, 0, 512, stream);

    k_degree<<<nbE, 256, 0, stream>>>(dst, deg, E);
    k_dinv<<<(N + 255) / 256, 256, 0, stream>>>(deg, dinv, N);
    k_scan_a<<<nbScan, 256, 0, stream>>>(deg, bsum, N);
    k_scan_b<<<1, 256, 0, stream>>>(bsum, boff, nbScan);
    k_scan_c<<<nbScan, 256, 0, stream>>>(deg, boff, offs, N);
    k_fill<<<nbE, 256, 0, stream>>>(src, dst, offs, cursor, csr, E);

    k_gemm1<<<(N + 127) / 128, 512, 0, stream>>>(x, W1, We, be, h1, xfc, N);
    k_agg1<<<(N + 3) / 4, 256, 0, stream>>>(csr, offs, deg, dinv, h1, xfc, b1, h, N);
    k_gemm2<<<(N + 127) / 128, 512, 0, stream>>>(h, W2, h2, N);
    k_agg2<<<(N + 15) / 16, 256, 0, stream>>>(csr, offs, deg, dinv, h2, h, b2, pooled, N);
    k_final<<<1, 64, 0, stream>>>(pooled, Wfc, bfc, out, 1.0f / (float)N);
}